// Round 1
// baseline (500.094 us; speedup 1.0000x reference)
//
#include <hip/hip_runtime.h>
#include <math.h>

// Problem constants
#define BB 32
#define SS 8
#define PP 32
#define SENT 44
#define LL 352          // SS*SENT
#define TT 384          // PP+LL
#define DD 2048
#define H1 512
#define H2 768
#define MM (BB*TT)      // 12288
#define OUT0 (MM*H2)    // 9437184

// ---------------------------------------------------------------------------
// GEMM1 (fused gather+add): H = tanh( gather(token_table)[+concat] @ W1 + b1 )
// A: [12288, 2048] virtual (gathered), W1: [2048,512], H: [12288,512]
// 64x64 tile, K-step 16, 256 threads, 4x4 micro-tile per thread.
// ---------------------------------------------------------------------------
__global__ __launch_bounds__(256) void gemm1_kernel(
    const float* __restrict__ token_table,
    const int*   __restrict__ topic_ids,
    const int*   __restrict__ input_ids,
    const float* __restrict__ concat_output,
    const float* __restrict__ W1,
    const float* __restrict__ b1,
    float*       __restrict__ Hout)
{
    const int bm = blockIdx.x;   // 0..191
    const int bn = blockIdx.y;   // 0..7
    const int tid = threadIdx.x;

    __shared__ float As[16][64];
    __shared__ float Bs[16][64];
    __shared__ const float* rowptr[64];
    __shared__ const float* addptr[64];

    if (tid < 64) {
        int m = bm * 64 + tid;
        int b = m / TT;
        int t = m % TT;
        int tok;
        const float* ap = nullptr;
        if (t < PP) {
            tok = topic_ids[b * PP + t];
        } else {
            int u = t - PP;
            tok = input_ids[b * LL + u];
            ap = concat_output + ((size_t)b * SS + (u / SENT)) * DD;
        }
        rowptr[tid] = token_table + (size_t)tok * DD;
        addptr[tid] = ap;
    }
    __syncthreads();

    const int tm = tid / 16;        // 0..15 -> rows tm*4..+3
    const int tn = tid % 16;        // cols tn*4..+3

    const int lr = tid >> 2;        // 0..63 A-load row
    const int lk = (tid & 3) * 4;   // A-load k quad
    const float* arow = rowptr[lr];
    const float* aadd = addptr[lr];

    const int bk = tid >> 4;        // 0..15 B-load k
    const int bc = (tid & 15) * 4;  // B-load col quad
    const float* wptr = W1 + (size_t)bk * H1 + bn * 64 + bc;

    float acc[4][4] = {};

    for (int k0 = 0; k0 < DD; k0 += 16) {
        float4 av = *(const float4*)(arow + k0 + lk);
        if (aadd) {
            float4 cv = *(const float4*)(aadd + k0 + lk);
            av.x += cv.x; av.y += cv.y; av.z += cv.z; av.w += cv.w;
        }
        float4 bv = *(const float4*)(wptr + (size_t)k0 * H1);

        __syncthreads();
        As[lk + 0][lr] = av.x;
        As[lk + 1][lr] = av.y;
        As[lk + 2][lr] = av.z;
        As[lk + 3][lr] = av.w;
        *(float4*)&Bs[bk][bc] = bv;
        __syncthreads();

        #pragma unroll
        for (int k = 0; k < 16; ++k) {
            float4 a = *(const float4*)&As[k][tm * 4];
            float4 w = *(const float4*)&Bs[k][tn * 4];
            acc[0][0] += a.x * w.x; acc[0][1] += a.x * w.y; acc[0][2] += a.x * w.z; acc[0][3] += a.x * w.w;
            acc[1][0] += a.y * w.x; acc[1][1] += a.y * w.y; acc[1][2] += a.y * w.z; acc[1][3] += a.y * w.w;
            acc[2][0] += a.z * w.x; acc[2][1] += a.z * w.y; acc[2][2] += a.z * w.z; acc[2][3] += a.z * w.w;
            acc[3][0] += a.w * w.x; acc[3][1] += a.w * w.y; acc[3][2] += a.w * w.z; acc[3][3] += a.w * w.w;
        }
    }

    #pragma unroll
    for (int i = 0; i < 4; ++i) {
        int row = bm * 64 + tm * 4 + i;
        #pragma unroll
        for (int j = 0; j < 4; ++j) {
            int col = bn * 64 + tn * 4 + j;
            Hout[(size_t)row * H1 + col] = tanhf(acc[i][j] + b1[col]);
        }
    }
}

// ---------------------------------------------------------------------------
// GEMM2: out = H @ W2 + b2   (H: [12288,512], W2: [512,768], out: [12288,768])
// ---------------------------------------------------------------------------
__global__ __launch_bounds__(256) void gemm2_kernel(
    const float* __restrict__ Hin,
    const float* __restrict__ W2,
    const float* __restrict__ b2,
    float*       __restrict__ out)
{
    const int bm = blockIdx.x;   // 0..191
    const int bn = blockIdx.y;   // 0..11
    const int tid = threadIdx.x;

    __shared__ float As[16][64];
    __shared__ float Bs[16][64];

    const int tm = tid / 16;
    const int tn = tid % 16;

    const int lr = tid >> 2;
    const int lk = (tid & 3) * 4;
    const float* arow = Hin + (size_t)(bm * 64 + lr) * H1;

    const int bk = tid >> 4;
    const int bc = (tid & 15) * 4;
    const float* wptr = W2 + (size_t)bk * H2 + bn * 64 + bc;

    float acc[4][4] = {};

    for (int k0 = 0; k0 < H1; k0 += 16) {
        float4 av = *(const float4*)(arow + k0 + lk);
        float4 bv = *(const float4*)(wptr + (size_t)k0 * H2);

        __syncthreads();
        As[lk + 0][lr] = av.x;
        As[lk + 1][lr] = av.y;
        As[lk + 2][lr] = av.z;
        As[lk + 3][lr] = av.w;
        *(float4*)&Bs[bk][bc] = bv;
        __syncthreads();

        #pragma unroll
        for (int k = 0; k < 16; ++k) {
            float4 a = *(const float4*)&As[k][tm * 4];
            float4 w = *(const float4*)&Bs[k][tn * 4];
            acc[0][0] += a.x * w.x; acc[0][1] += a.x * w.y; acc[0][2] += a.x * w.z; acc[0][3] += a.x * w.w;
            acc[1][0] += a.y * w.x; acc[1][1] += a.y * w.y; acc[1][2] += a.y * w.z; acc[1][3] += a.y * w.w;
            acc[2][0] += a.z * w.x; acc[2][1] += a.z * w.y; acc[2][2] += a.z * w.z; acc[2][3] += a.z * w.w;
            acc[3][0] += a.w * w.x; acc[3][1] += a.w * w.y; acc[3][2] += a.w * w.z; acc[3][3] += a.w * w.w;
        }
    }

    #pragma unroll
    for (int i = 0; i < 4; ++i) {
        int row = bm * 64 + tm * 4 + i;
        #pragma unroll
        for (int j = 0; j < 4; ++j) {
            int col = bn * 64 + tn * 4 + j;
            out[(size_t)row * H2 + col] = acc[i][j] + b2[col];
        }
    }
}

// ---------------------------------------------------------------------------
// Aux outputs: labels / type_ids / att_mask concatenations, written as floats
// ---------------------------------------------------------------------------
__global__ __launch_bounds__(256) void aux_kernel(
    const int* __restrict__ topic_ids,
    const int* __restrict__ input_ids,
    const int* __restrict__ tpw_type_ids,
    const int* __restrict__ type_ids,
    const int* __restrict__ tpw_att_mask,
    const int* __restrict__ attention_mask,
    float* __restrict__ out)
{
    int idx = blockIdx.x * 256 + threadIdx.x;
    if (idx >= MM) return;
    int b = idx / TT, t = idx % TT;
    int lab, ty, mk;
    if (t < PP) {
        lab = topic_ids[b * PP + t];
        ty  = tpw_type_ids[b * PP + t];
        mk  = tpw_att_mask[b * PP + t];
    } else {
        int u = t - PP;
        lab = input_ids[b * LL + u];
        ty  = type_ids[b * LL + u];
        mk  = attention_mask[b * LL + u];
    }
    out[OUT0 + idx]          = (float)lab;
    out[OUT0 + MM + idx]     = (float)ty;
    out[OUT0 + 2 * MM + idx] = (float)mk;
}

extern "C" void kernel_launch(void* const* d_in, const int* in_sizes, int n_in,
                              void* d_out, int out_size, void* d_ws, size_t ws_size,
                              hipStream_t stream) {
    const float* concat_output  = (const float*)d_in[0];
    const int*   input_ids      = (const int*)d_in[1];
    const int*   topic_ids      = (const int*)d_in[2];
    const int*   tpw_att_mask   = (const int*)d_in[3];
    const int*   tpw_type_ids   = (const int*)d_in[4];
    const int*   attention_mask = (const int*)d_in[5];
    const int*   type_ids       = (const int*)d_in[6];
    const float* token_table    = (const float*)d_in[7];
    const float* W1             = (const float*)d_in[8];
    const float* b1             = (const float*)d_in[9];
    const float* W2             = (const float*)d_in[10];
    const float* b2             = (const float*)d_in[11];
    float* out = (float*)d_out;
    float* Hws = (float*)d_ws;   // 12288*512 f32 = 25.2 MB

    gemm1_kernel<<<dim3(MM / 64, H1 / 64), 256, 0, stream>>>(
        token_table, topic_ids, input_ids, concat_output, W1, b1, Hws);
    gemm2_kernel<<<dim3(MM / 64, H2 / 64), 256, 0, stream>>>(
        Hws, W2, b2, out);
    aux_kernel<<<(MM + 255) / 256, 256, 0, stream>>>(
        topic_ids, input_ids, tpw_type_ids, type_ids, tpw_att_mask, attention_mask, out);
}

// Round 2
// 240.262 us; speedup vs baseline: 2.0814x; 2.0814x over previous
//
#include <hip/hip_runtime.h>
#include <math.h>

typedef _Float16 half8 __attribute__((ext_vector_type(8)));
typedef float f32x4 __attribute__((ext_vector_type(4)));

// Problem constants
#define BB 32
#define SS 8
#define PP 32
#define SENT 44
#define LL 352          // SS*SENT
#define TT 384          // PP+LL
#define DD 2048
#define H1 512
#define H2 768
#define MM (BB*TT)      // 12288
#define OUT0 (MM*H2)    // 9437184

#define LDSTRIDE 72     // 64 + 8 pad halfs -> 144B row stride (odd multiple of 16B)

// ---------------------------------------------------------------------------
// Transpose + fp32->fp16 convert:  dst[C][R] = (f16) src[R][C]
// ---------------------------------------------------------------------------
__global__ __launch_bounds__(256) void transpose_f16_kernel(
    const float* __restrict__ src, _Float16* __restrict__ dst, int R, int C)
{
    __shared__ float tile[32][33];
    int c0 = blockIdx.x * 32;
    int r0 = blockIdx.y * 32;
    int tx = threadIdx.x & 31;
    int ty = threadIdx.x >> 5;   // 0..7
    #pragma unroll
    for (int i = 0; i < 4; ++i)
        tile[ty + i*8][tx] = src[(size_t)(r0 + ty + i*8) * C + c0 + tx];
    __syncthreads();
    #pragma unroll
    for (int i = 0; i < 4; ++i)
        dst[(size_t)(c0 + ty + i*8) * R + r0 + tx] = (_Float16)tile[tx][ty + i*8];
}

// ---------------------------------------------------------------------------
// GEMM1 (fused gather+add+convert): H = tanh( A @ W1 + b1 ), A gathered fp32
// A virtual [12288,2048], W1T f16 [512][2048] (K-contig), H f16 [12288][512]
// 128x128 tile, BK=64, 256 threads = 4 waves, each wave 64x64 via 4x4 frags
// of mfma_f32_16x16x32_f16.
// ---------------------------------------------------------------------------
__global__ __launch_bounds__(256) void gemm1_kernel(
    const float*    __restrict__ token_table,
    const int*      __restrict__ topic_ids,
    const int*      __restrict__ input_ids,
    const float*    __restrict__ concat_output,
    const _Float16* __restrict__ W1T,
    const float*    __restrict__ b1,
    _Float16*       __restrict__ Hout)
{
    const int tid = threadIdx.x;
    // XCD-chunked swizzle: 384 blocks, 48 per XCD chunk (384 % 8 == 0)
    const int logical = ((blockIdx.x & 7) * 48) + (blockIdx.x >> 3);
    const int bm = logical >> 2;     // 0..95
    const int bn = logical & 3;      // 0..3

    __shared__ _Float16 As[128 * LDSTRIDE];
    __shared__ _Float16 Bs[128 * LDSTRIDE];

    // --- staging assignment: 2 threads per A/B row ---
    const int srow = tid >> 1;          // 0..127
    const int skb  = (tid & 1) * 32;    // k-offset within BK=64

    int m = bm * 128 + srow;
    int b = m / TT;
    int t = m % TT;
    const float* aptr;
    const float* addp = nullptr;
    if (t < PP) {
        aptr = token_table + (size_t)topic_ids[b * PP + t] * DD;
    } else {
        int u = t - PP;
        aptr = token_table + (size_t)input_ids[b * LL + u] * DD;
        addp = concat_output + ((size_t)b * SS + (u / SENT)) * DD;
    }
    const _Float16* bptr = W1T + (size_t)(bn * 128 + srow) * DD;

    // --- compute assignment ---
    const int wid  = tid >> 6;
    const int lane = tid & 63;
    const int wrow = (wid >> 1) * 64;
    const int wcol = (wid & 1) * 64;
    const int fr   = lane & 15;
    const int fg   = lane >> 4;

    f32x4 acc[4][4] = {};

    for (int k0 = 0; k0 < DD; k0 += 64) {
        // global -> regs
        float a[32];
        #pragma unroll
        for (int q = 0; q < 8; ++q) {
            float4 v = *(const float4*)(aptr + k0 + skb + q * 4);
            a[q*4+0] = v.x; a[q*4+1] = v.y; a[q*4+2] = v.z; a[q*4+3] = v.w;
        }
        if (addp) {
            #pragma unroll
            for (int q = 0; q < 8; ++q) {
                float4 v = *(const float4*)(addp + k0 + skb + q * 4);
                a[q*4+0] += v.x; a[q*4+1] += v.y; a[q*4+2] += v.z; a[q*4+3] += v.w;
            }
        }
        uint4 bv[4];
        #pragma unroll
        for (int q = 0; q < 4; ++q)
            bv[q] = *(const uint4*)(bptr + k0 + skb + q * 8);

        __syncthreads();   // previous iteration's reads done
        {
            _Float16* ad = &As[srow * LDSTRIDE + skb];
            #pragma unroll
            for (int q = 0; q < 4; ++q) {
                half8 h;
                #pragma unroll
                for (int j = 0; j < 8; ++j) h[j] = (_Float16)a[q*8 + j];
                *(half8*)(ad + q * 8) = h;
            }
            uint4* bd = (uint4*)&Bs[srow * LDSTRIDE + skb];
            #pragma unroll
            for (int q = 0; q < 4; ++q) bd[q] = bv[q];
        }
        __syncthreads();   // tile ready

        #pragma unroll
        for (int kk = 0; kk < 2; ++kk) {
            half8 af[4], bf[4];
            #pragma unroll
            for (int i = 0; i < 4; ++i)
                af[i] = *(const half8*)&As[(wrow + i*16 + fr) * LDSTRIDE + kk*32 + fg*8];
            #pragma unroll
            for (int j = 0; j < 4; ++j)
                bf[j] = *(const half8*)&Bs[(wcol + j*16 + fr) * LDSTRIDE + kk*32 + fg*8];
            #pragma unroll
            for (int i = 0; i < 4; ++i)
                #pragma unroll
                for (int j = 0; j < 4; ++j)
                    acc[i][j] = __builtin_amdgcn_mfma_f32_16x16x32_f16(af[i], bf[j], acc[i][j], 0, 0, 0);
        }
    }

    // epilogue: bias + tanh -> f16 H
    #pragma unroll
    for (int i = 0; i < 4; ++i) {
        #pragma unroll
        for (int j = 0; j < 4; ++j) {
            int col = bn * 128 + wcol + j * 16 + fr;
            float bias = b1[col];
            #pragma unroll
            for (int r = 0; r < 4; ++r) {
                int row = bm * 128 + wrow + i * 16 + fg * 4 + r;
                Hout[(size_t)row * H1 + col] = (_Float16)tanhf(acc[i][j][r] + bias);
            }
        }
    }
}

// ---------------------------------------------------------------------------
// GEMM2: out = H @ W2 + b2.  H f16 [12288][512], W2T f16 [768][512],
// out fp32 [12288][768]. Same structure, BK=64 (8 iters).
// ---------------------------------------------------------------------------
__global__ __launch_bounds__(256) void gemm2_kernel(
    const _Float16* __restrict__ Hin,
    const _Float16* __restrict__ W2T,
    const float*    __restrict__ b2,
    float*          __restrict__ out)
{
    const int tid = threadIdx.x;
    // 576 blocks, 72 per XCD chunk (576 % 8 == 0)
    const int logical = ((blockIdx.x & 7) * 72) + (blockIdx.x >> 3);
    const int bm = logical / 6;      // 0..95
    const int bn = logical % 6;      // 0..5

    __shared__ _Float16 As[128 * LDSTRIDE];
    __shared__ _Float16 Bs[128 * LDSTRIDE];

    const int srow = tid >> 1;
    const int skb  = (tid & 1) * 32;
    const _Float16* aptr = Hin + (size_t)(bm * 128 + srow) * H1;
    const _Float16* bptr = W2T + (size_t)(bn * 128 + srow) * H1;

    const int wid  = tid >> 6;
    const int lane = tid & 63;
    const int wrow = (wid >> 1) * 64;
    const int wcol = (wid & 1) * 64;
    const int fr   = lane & 15;
    const int fg   = lane >> 4;

    f32x4 acc[4][4] = {};

    for (int k0 = 0; k0 < H1; k0 += 64) {
        uint4 av[4], bv[4];
        #pragma unroll
        for (int q = 0; q < 4; ++q) {
            av[q] = *(const uint4*)(aptr + k0 + skb + q * 8);
            bv[q] = *(const uint4*)(bptr + k0 + skb + q * 8);
        }

        __syncthreads();
        {
            uint4* ad = (uint4*)&As[srow * LDSTRIDE + skb];
            uint4* bd = (uint4*)&Bs[srow * LDSTRIDE + skb];
            #pragma unroll
            for (int q = 0; q < 4; ++q) { ad[q] = av[q]; bd[q] = bv[q]; }
        }
        __syncthreads();

        #pragma unroll
        for (int kk = 0; kk < 2; ++kk) {
            half8 af[4], bf[4];
            #pragma unroll
            for (int i = 0; i < 4; ++i)
                af[i] = *(const half8*)&As[(wrow + i*16 + fr) * LDSTRIDE + kk*32 + fg*8];
            #pragma unroll
            for (int j = 0; j < 4; ++j)
                bf[j] = *(const half8*)&Bs[(wcol + j*16 + fr) * LDSTRIDE + kk*32 + fg*8];
            #pragma unroll
            for (int i = 0; i < 4; ++i)
                #pragma unroll
                for (int j = 0; j < 4; ++j)
                    acc[i][j] = __builtin_amdgcn_mfma_f32_16x16x32_f16(af[i], bf[j], acc[i][j], 0, 0, 0);
        }
    }

    #pragma unroll
    for (int i = 0; i < 4; ++i) {
        #pragma unroll
        for (int j = 0; j < 4; ++j) {
            int col = bn * 128 + wcol + j * 16 + fr;
            float bias = b2[col];
            #pragma unroll
            for (int r = 0; r < 4; ++r) {
                int row = bm * 128 + wrow + i * 16 + fg * 4 + r;
                out[(size_t)row * H2 + col] = acc[i][j][r] + bias;
            }
        }
    }
}

// ---------------------------------------------------------------------------
// Aux outputs: labels / type_ids / att_mask concatenations, written as floats
// ---------------------------------------------------------------------------
__global__ __launch_bounds__(256) void aux_kernel(
    const int* __restrict__ topic_ids,
    const int* __restrict__ input_ids,
    const int* __restrict__ tpw_type_ids,
    const int* __restrict__ type_ids,
    const int* __restrict__ tpw_att_mask,
    const int* __restrict__ attention_mask,
    float* __restrict__ out)
{
    int idx = blockIdx.x * 256 + threadIdx.x;
    if (idx >= MM) return;
    int b = idx / TT, t = idx % TT;
    int lab, ty, mk;
    if (t < PP) {
        lab = topic_ids[b * PP + t];
        ty  = tpw_type_ids[b * PP + t];
        mk  = tpw_att_mask[b * PP + t];
    } else {
        int u = t - PP;
        lab = input_ids[b * LL + u];
        ty  = type_ids[b * LL + u];
        mk  = attention_mask[b * LL + u];
    }
    out[OUT0 + idx]          = (float)lab;
    out[OUT0 + MM + idx]     = (float)ty;
    out[OUT0 + 2 * MM + idx] = (float)mk;
}

extern "C" void kernel_launch(void* const* d_in, const int* in_sizes, int n_in,
                              void* d_out, int out_size, void* d_ws, size_t ws_size,
                              hipStream_t stream) {
    const float* concat_output  = (const float*)d_in[0];
    const int*   input_ids      = (const int*)d_in[1];
    const int*   topic_ids      = (const int*)d_in[2];
    const int*   tpw_att_mask   = (const int*)d_in[3];
    const int*   tpw_type_ids   = (const int*)d_in[4];
    const int*   attention_mask = (const int*)d_in[5];
    const int*   type_ids       = (const int*)d_in[6];
    const float* token_table    = (const float*)d_in[7];
    const float* W1             = (const float*)d_in[8];
    const float* b1             = (const float*)d_in[9];
    const float* W2             = (const float*)d_in[10];
    const float* b2             = (const float*)d_in[11];
    float* out = (float*)d_out;

    _Float16* w1t = (_Float16*)d_ws;            // [512][2048]  2.0 MB
    _Float16* w2t = w1t + (size_t)H1 * DD;      // [768][512]   0.75 MB
    _Float16* Hws = w2t + (size_t)H2 * H1;      // [12288][512] 12.6 MB

    transpose_f16_kernel<<<dim3(H1 / 32, DD / 32), 256, 0, stream>>>(W1, w1t, DD, H1);
    transpose_f16_kernel<<<dim3(H2 / 32, H1 / 32), 256, 0, stream>>>(W2, w2t, H1, H2);
    aux_kernel<<<(MM + 255) / 256, 256, 0, stream>>>(
        topic_ids, input_ids, tpw_type_ids, type_ids, tpw_att_mask, attention_mask, out);

    gemm1_kernel<<<MM / 128 * (H1 / 128), 256, 0, stream>>>(
        token_table, topic_ids, input_ids, concat_output, w1t, b1, Hws);
    gemm2_kernel<<<MM / 128 * (H2 / 128), 256, 0, stream>>>(
        Hws, w2t, b2, out);
}

// Round 3
// 148.502 us; speedup vs baseline: 3.3676x; 1.6179x over previous
//
#include <hip/hip_runtime.h>
#include <math.h>

typedef _Float16 half8 __attribute__((ext_vector_type(8)));
typedef float f32x4 __attribute__((ext_vector_type(4)));

// Problem constants
#define BB 32
#define SS 8
#define PP 32
#define SENT 44
#define LL 352          // SS*SENT
#define TT 384          // PP+LL
#define DD 2048
#define H1 512
#define H2 768
#define MM (BB*TT)      // 12288
#define OUT0 (MM*H2)    // 9437184

#define LDST 72         // 64 + 8 pad halfs -> 144B row stride (odd multiple of 16B)

// ---------------------------------------------------------------------------
// Transpose + fp32->fp16 convert:  dst[C][R] = (f16) src[R][C]
// ---------------------------------------------------------------------------
__global__ __launch_bounds__(256) void transpose_f16_kernel(
    const float* __restrict__ src, _Float16* __restrict__ dst, int R, int C)
{
    __shared__ float tile[32][33];
    int c0 = blockIdx.x * 32;
    int r0 = blockIdx.y * 32;
    int tx = threadIdx.x & 31;
    int ty = threadIdx.x >> 5;   // 0..7
    #pragma unroll
    for (int i = 0; i < 4; ++i)
        tile[ty + i*8][tx] = src[(size_t)(r0 + ty + i*8) * C + c0 + tx];
    __syncthreads();
    #pragma unroll
    for (int i = 0; i < 4; ++i)
        dst[(size_t)(c0 + ty + i*8) * R + r0 + tx] = (_Float16)tile[tx][ty + i*8];
}

// ---------------------------------------------------------------------------
// GEMM1 (fused gather+add+convert): H = tanh( A @ W1 + b1 )
// A virtual [12288,2048] fp32 (gathered), W1T f16 [512][2048], H f16 [12288][512]
// 64x64 tile, BK=64, 256 threads = 4 waves, wave = 32x32 via 2x2 frags of
// mfma_f32_16x16x32_f16. Reg-staged double-buffered LDS, 1 barrier/iter.
// ---------------------------------------------------------------------------
__global__ __launch_bounds__(256) void gemm1_kernel(
    const float*    __restrict__ token_table,
    const int*      __restrict__ topic_ids,
    const int*      __restrict__ input_ids,
    const float*    __restrict__ concat_output,
    const _Float16* __restrict__ W1T,
    const float*    __restrict__ b1,
    _Float16*       __restrict__ Hout)
{
    const int tid = threadIdx.x;
    // XCD-chunked bijective swizzle: 1536 blocks, 192 per XCD
    const int logical = ((blockIdx.x & 7) * 192) + (blockIdx.x >> 3);
    const int bm = logical >> 3;     // 0..191
    const int bn = logical & 7;      // 0..7

    __shared__ _Float16 As[2][64 * LDST];
    __shared__ _Float16 Bs[2][64 * LDST];

    // --- staging assignment: 4 threads per row, 16 elems each ---
    const int srow = tid >> 2;          // 0..63
    const int skb  = (tid & 3) * 16;    // k-offset within BK=64

    int m = bm * 64 + srow;
    int b = m / TT;
    int t = m % TT;
    const float* aptr;
    const float* addp = nullptr;
    if (t < PP) {
        aptr = token_table + (size_t)topic_ids[b * PP + t] * DD;
    } else {
        int u = t - PP;
        aptr = token_table + (size_t)input_ids[b * LL + u] * DD;
        addp = concat_output + ((size_t)b * SS + (u / SENT)) * DD;
    }
    const _Float16* bptr = W1T + (size_t)(bn * 64 + srow) * DD;

    // --- compute assignment ---
    const int wid  = tid >> 6;
    const int lane = tid & 63;
    const int wrow = (wid >> 1) * 32;
    const int wcol = (wid & 1) * 32;
    const int fr   = lane & 15;
    const int fg   = lane >> 4;

    f32x4 acc[2][2] = {};
    float a[16];
    uint4 bstage[2];

    #define G1_LOAD(k0)                                                        \
        {                                                                      \
            _Pragma("unroll")                                                  \
            for (int q = 0; q < 4; ++q) {                                      \
                float4 v = *(const float4*)(aptr + (k0) + skb + q * 4);        \
                a[q*4+0] = v.x; a[q*4+1] = v.y; a[q*4+2] = v.z; a[q*4+3] = v.w;\
            }                                                                  \
            if (addp) {                                                        \
                _Pragma("unroll")                                              \
                for (int q = 0; q < 4; ++q) {                                  \
                    float4 v = *(const float4*)(addp + (k0) + skb + q * 4);    \
                    a[q*4+0] += v.x; a[q*4+1] += v.y;                          \
                    a[q*4+2] += v.z; a[q*4+3] += v.w;                          \
                }                                                              \
            }                                                                  \
            bstage[0] = *(const uint4*)(bptr + (k0) + skb);                    \
            bstage[1] = *(const uint4*)(bptr + (k0) + skb + 8);                \
        }

    #define G1_WRITE(buf)                                                      \
        {                                                                      \
            _Float16* ad = &As[buf][srow * LDST + skb];                        \
            half8 h0, h1;                                                      \
            _Pragma("unroll")                                                  \
            for (int j = 0; j < 8; ++j) { h0[j] = (_Float16)a[j];              \
                                          h1[j] = (_Float16)a[8+j]; }          \
            *(half8*)ad = h0;                                                  \
            *(half8*)(ad + 8) = h1;                                            \
            uint4* bd = (uint4*)&Bs[buf][srow * LDST + skb];                   \
            bd[0] = bstage[0]; bd[1] = bstage[1];                              \
        }

    #define G1_COMPUTE(buf)                                                    \
        {                                                                      \
            _Pragma("unroll")                                                  \
            for (int kk = 0; kk < 2; ++kk) {                                   \
                half8 af[2], bf[2];                                            \
                _Pragma("unroll")                                              \
                for (int i = 0; i < 2; ++i)                                    \
                    af[i] = *(const half8*)&As[buf][(wrow + i*16 + fr) * LDST + kk*32 + fg*8]; \
                _Pragma("unroll")                                              \
                for (int j = 0; j < 2; ++j)                                    \
                    bf[j] = *(const half8*)&Bs[buf][(wcol + j*16 + fr) * LDST + kk*32 + fg*8]; \
                _Pragma("unroll")                                              \
                for (int i = 0; i < 2; ++i)                                    \
                    _Pragma("unroll")                                          \
                    for (int j = 0; j < 2; ++j)                                \
                        acc[i][j] = __builtin_amdgcn_mfma_f32_16x16x32_f16(af[i], bf[j], acc[i][j], 0, 0, 0); \
            }                                                                  \
        }

    G1_LOAD(0);
    G1_WRITE(0);
    __syncthreads();

    int cur = 0;
    const int NT = DD / 64;   // 32
    for (int tt = 0; tt < NT; ++tt) {
        if (tt + 1 < NT) G1_LOAD((tt + 1) * 64);
        G1_COMPUTE(cur);
        if (tt + 1 < NT) G1_WRITE(cur ^ 1);
        __syncthreads();
        cur ^= 1;
    }

    // epilogue: bias + tanh -> f16 H
    #pragma unroll
    for (int i = 0; i < 2; ++i) {
        #pragma unroll
        for (int j = 0; j < 2; ++j) {
            int col = bn * 64 + wcol + j * 16 + fr;
            float bias = b1[col];
            #pragma unroll
            for (int r = 0; r < 4; ++r) {
                int row = bm * 64 + wrow + i * 16 + fg * 4 + r;
                Hout[(size_t)row * H1 + col] = (_Float16)tanhf(acc[i][j][r] + bias);
            }
        }
    }
}

// ---------------------------------------------------------------------------
// GEMM2: out = H @ W2 + b2.  H f16 [12288][512], W2T f16 [768][512],
// out fp32 [12288][768]. Same 64x64 dbuf structure, 8 K-iters.
// ---------------------------------------------------------------------------
__global__ __launch_bounds__(256) void gemm2_kernel(
    const _Float16* __restrict__ Hin,
    const _Float16* __restrict__ W2T,
    const float*    __restrict__ b2,
    float*          __restrict__ out)
{
    const int tid = threadIdx.x;
    // 2304 blocks, 288 per XCD
    const int logical = ((blockIdx.x & 7) * 288) + (blockIdx.x >> 3);
    const int bm = logical / 12;     // 0..191
    const int bn = logical % 12;     // 0..11

    __shared__ _Float16 As[2][64 * LDST];
    __shared__ _Float16 Bs[2][64 * LDST];

    const int srow = tid >> 2;
    const int skb  = (tid & 3) * 16;
    const _Float16* aptr = Hin + (size_t)(bm * 64 + srow) * H1;
    const _Float16* bptr = W2T + (size_t)(bn * 64 + srow) * H1;

    const int wid  = tid >> 6;
    const int lane = tid & 63;
    const int wrow = (wid >> 1) * 32;
    const int wcol = (wid & 1) * 32;
    const int fr   = lane & 15;
    const int fg   = lane >> 4;

    f32x4 acc[2][2] = {};
    uint4 astage[2], bstage[2];

    #define G2_LOAD(k0)                                                        \
        {                                                                      \
            astage[0] = *(const uint4*)(aptr + (k0) + skb);                    \
            astage[1] = *(const uint4*)(aptr + (k0) + skb + 8);                \
            bstage[0] = *(const uint4*)(bptr + (k0) + skb);                    \
            bstage[1] = *(const uint4*)(bptr + (k0) + skb + 8);                \
        }

    #define G2_WRITE(buf)                                                      \
        {                                                                      \
            uint4* ad = (uint4*)&As[buf][srow * LDST + skb];                   \
            uint4* bd = (uint4*)&Bs[buf][srow * LDST + skb];                   \
            ad[0] = astage[0]; ad[1] = astage[1];                              \
            bd[0] = bstage[0]; bd[1] = bstage[1];                              \
        }

    G2_LOAD(0);
    G2_WRITE(0);
    __syncthreads();

    int cur = 0;
    const int NT = H1 / 64;   // 8
    for (int tt = 0; tt < NT; ++tt) {
        if (tt + 1 < NT) G2_LOAD((tt + 1) * 64);
        {
            #pragma unroll
            for (int kk = 0; kk < 2; ++kk) {
                half8 af[2], bf[2];
                #pragma unroll
                for (int i = 0; i < 2; ++i)
                    af[i] = *(const half8*)&As[cur][(wrow + i*16 + fr) * LDST + kk*32 + fg*8];
                #pragma unroll
                for (int j = 0; j < 2; ++j)
                    bf[j] = *(const half8*)&Bs[cur][(wcol + j*16 + fr) * LDST + kk*32 + fg*8];
                #pragma unroll
                for (int i = 0; i < 2; ++i)
                    #pragma unroll
                    for (int j = 0; j < 2; ++j)
                        acc[i][j] = __builtin_amdgcn_mfma_f32_16x16x32_f16(af[i], bf[j], acc[i][j], 0, 0, 0);
            }
        }
        if (tt + 1 < NT) G2_WRITE(cur ^ 1);
        __syncthreads();
        cur ^= 1;
    }

    #pragma unroll
    for (int i = 0; i < 2; ++i) {
        #pragma unroll
        for (int j = 0; j < 2; ++j) {
            int col = bn * 64 + wcol + j * 16 + fr;
            float bias = b2[col];
            #pragma unroll
            for (int r = 0; r < 4; ++r) {
                int row = bm * 64 + wrow + i * 16 + fg * 4 + r;
                out[(size_t)row * H2 + col] = acc[i][j][r] + bias;
            }
        }
    }
}

// ---------------------------------------------------------------------------
// Aux outputs: labels / type_ids / att_mask concatenations, written as floats
// ---------------------------------------------------------------------------
__global__ __launch_bounds__(256) void aux_kernel(
    const int* __restrict__ topic_ids,
    const int* __restrict__ input_ids,
    const int* __restrict__ tpw_type_ids,
    const int* __restrict__ type_ids,
    const int* __restrict__ tpw_att_mask,
    const int* __restrict__ attention_mask,
    float* __restrict__ out)
{
    int idx = blockIdx.x * 256 + threadIdx.x;
    if (idx >= MM) return;
    int b = idx / TT, t = idx % TT;
    int lab, ty, mk;
    if (t < PP) {
        lab = topic_ids[b * PP + t];
        ty  = tpw_type_ids[b * PP + t];
        mk  = tpw_att_mask[b * PP + t];
    } else {
        int u = t - PP;
        lab = input_ids[b * LL + u];
        ty  = type_ids[b * LL + u];
        mk  = attention_mask[b * LL + u];
    }
    out[OUT0 + idx]          = (float)lab;
    out[OUT0 + MM + idx]     = (float)ty;
    out[OUT0 + 2 * MM + idx] = (float)mk;
}

extern "C" void kernel_launch(void* const* d_in, const int* in_sizes, int n_in,
                              void* d_out, int out_size, void* d_ws, size_t ws_size,
                              hipStream_t stream) {
    const float* concat_output  = (const float*)d_in[0];
    const int*   input_ids      = (const int*)d_in[1];
    const int*   topic_ids      = (const int*)d_in[2];
    const int*   tpw_att_mask   = (const int*)d_in[3];
    const int*   tpw_type_ids   = (const int*)d_in[4];
    const int*   attention_mask = (const int*)d_in[5];
    const int*   type_ids       = (const int*)d_in[6];
    const float* token_table    = (const float*)d_in[7];
    const float* W1             = (const float*)d_in[8];
    const float* b1             = (const float*)d_in[9];
    const float* W2             = (const float*)d_in[10];
    const float* b2             = (const float*)d_in[11];
    float* out = (float*)d_out;

    _Float16* w1t = (_Float16*)d_ws;            // [512][2048]  2.0 MB
    _Float16* w2t = w1t + (size_t)H1 * DD;      // [768][512]   0.75 MB
    _Float16* Hws = w2t + (size_t)H2 * H1;      // [12288][512] 12.6 MB

    transpose_f16_kernel<<<dim3(H1 / 32, DD / 32), 256, 0, stream>>>(W1, w1t, DD, H1);
    transpose_f16_kernel<<<dim3(H2 / 32, H1 / 32), 256, 0, stream>>>(W2, w2t, H1, H2);
    aux_kernel<<<(MM + 255) / 256, 256, 0, stream>>>(
        topic_ids, input_ids, tpw_type_ids, type_ids, tpw_att_mask, attention_mask, out);

    gemm1_kernel<<<(MM / 64) * (H1 / 64), 256, 0, stream>>>(
        token_table, topic_ids, input_ids, concat_output, w1t, b1, Hws);
    gemm2_kernel<<<(MM / 64) * (H2 / 64), 256, 0, stream>>>(
        Hws, w2t, b2, out);
}

// Round 4
// 114.809 us; speedup vs baseline: 4.3559x; 1.2935x over previous
//
#include <hip/hip_runtime.h>
#include <math.h>

typedef _Float16 half8 __attribute__((ext_vector_type(8)));
typedef float f32x4 __attribute__((ext_vector_type(4)));

// Problem constants
#define BB 32
#define SS 8
#define PP 32
#define SENT 44
#define LL 352          // SS*SENT
#define TT 384          // PP+LL
#define DD 2048
#define H1 512
#define H2 768
#define MM (BB*TT)      // 12288
#define OUT0 (MM*H2)    // 9437184

// async global->LDS, 16B per lane, dest = wave-uniform base + lane*16
#define GLL16(g, l) __builtin_amdgcn_global_load_lds( \
    (const __attribute__((address_space(1))) void*)(g), \
    (__attribute__((address_space(3))) void*)(l), 16, 0, 0)

// ---------------------------------------------------------------------------
// Gather + concat-add + fp32->f16:  A16[m][k] for m in [0,12288), k in [0,2048)
// One block per row, 256 threads x 8 elems. Fully coalesced streaming.
// ---------------------------------------------------------------------------
__global__ __launch_bounds__(256) void gather_kernel(
    const float* __restrict__ token_table,
    const int*   __restrict__ topic_ids,
    const int*   __restrict__ input_ids,
    const float* __restrict__ concat_output,
    _Float16*    __restrict__ A16)
{
    const int m = blockIdx.x;
    const int b = m / TT;
    const int t = m % TT;
    const float* src;
    const float* addp = nullptr;
    if (t < PP) {
        src = token_table + (size_t)topic_ids[b * PP + t] * DD;
    } else {
        int u = t - PP;
        src = token_table + (size_t)input_ids[b * LL + u] * DD;
        addp = concat_output + ((size_t)b * SS + (u / SENT)) * DD;
    }
    _Float16* dst = A16 + (size_t)m * DD;
    const int base = threadIdx.x * 8;
    float4 v0 = *(const float4*)(src + base);
    float4 v1 = *(const float4*)(src + base + 4);
    if (addp) {
        float4 c0 = *(const float4*)(addp + base);
        float4 c1 = *(const float4*)(addp + base + 4);
        v0.x += c0.x; v0.y += c0.y; v0.z += c0.z; v0.w += c0.w;
        v1.x += c1.x; v1.y += c1.y; v1.z += c1.z; v1.w += c1.w;
    }
    half8 h;
    h[0] = (_Float16)v0.x; h[1] = (_Float16)v0.y; h[2] = (_Float16)v0.z; h[3] = (_Float16)v0.w;
    h[4] = (_Float16)v1.x; h[5] = (_Float16)v1.y; h[6] = (_Float16)v1.z; h[7] = (_Float16)v1.w;
    *(half8*)(dst + base) = h;
}

// ---------------------------------------------------------------------------
// Transpose + fp32->fp16 convert:  dst[C][R] = (f16) src[R][C]
// ---------------------------------------------------------------------------
__global__ __launch_bounds__(256) void transpose_f16_kernel(
    const float* __restrict__ src, _Float16* __restrict__ dst, int R, int C)
{
    __shared__ float tile[32][33];
    int c0 = blockIdx.x * 32;
    int r0 = blockIdx.y * 32;
    int tx = threadIdx.x & 31;
    int ty = threadIdx.x >> 5;   // 0..7
    #pragma unroll
    for (int i = 0; i < 4; ++i)
        tile[ty + i*8][tx] = src[(size_t)(r0 + ty + i*8) * C + c0 + tx];
    __syncthreads();
    #pragma unroll
    for (int i = 0; i < 4; ++i)
        dst[(size_t)(c0 + ty + i*8) * R + r0 + tx] = (_Float16)tile[tx][ty + i*8];
}

// ---------------------------------------------------------------------------
// GEMM1: H = tanh( A16 @ W1 + b1 ).  A16 f16 [12288][2048], W1T f16 [512][2048],
// H f16 [12288][512]. Tile 64x128, BK=64, 256 thr = 4 waves, wave = 32x64
// (2x4 frags of mfma_f32_16x16x32_f16). global_load_lds staging, dbuf,
// 1 barrier per K-iter. Grid 768 = 3 blocks/CU (LDS 48KB).
// ---------------------------------------------------------------------------
__global__ __launch_bounds__(256) void gemm1_kernel(
    const _Float16* __restrict__ A16,
    const _Float16* __restrict__ W1T,
    const float*    __restrict__ b1,
    _Float16*       __restrict__ Hout)
{
    const int tid  = threadIdx.x;
    const int wid  = tid >> 6;
    const int lane = tid & 63;

    // XCD-chunked bijective swizzle: 768 blocks, 96 per XCD; all 4 bn of a bm
    // land on the same XCD.
    const int logical = ((blockIdx.x & 7) * 96) + (blockIdx.x >> 3);
    const int bm = logical >> 2;     // 0..191
    const int bn = logical & 3;      // 0..3

    __shared__ _Float16 As[2][64 * 64];    // 8KB per buf
    __shared__ _Float16 Bs[2][128 * 64];   // 16KB per buf

    // --- staging: 1KB chunks, lane l -> 16B at chunk_base + l*16 ---
    const int lrow = lane >> 3;          // row within 8-row chunk
    const int lcol = (lane & 7) * 8;     // halfs within row
    const _Float16* ag0 = A16 + (size_t)(bm * 64 + wid * 8       + lrow) * DD + lcol;
    const _Float16* ag1 = A16 + (size_t)(bm * 64 + (wid + 4) * 8 + lrow) * DD + lcol;
    const _Float16* bg0 = W1T + (size_t)(bn * 128 +  wid       * 8 + lrow) * DD + lcol;
    const _Float16* bg1 = W1T + (size_t)(bn * 128 + (wid +  4) * 8 + lrow) * DD + lcol;
    const _Float16* bg2 = W1T + (size_t)(bn * 128 + (wid +  8) * 8 + lrow) * DD + lcol;
    const _Float16* bg3 = W1T + (size_t)(bn * 128 + (wid + 12) * 8 + lrow) * DD + lcol;

    #define G1_ISSUE(buf, k0) {                                        \
        GLL16(ag0 + (k0), &As[buf][ wid      * 512]);                  \
        GLL16(ag1 + (k0), &As[buf][(wid + 4) * 512]);                  \
        GLL16(bg0 + (k0), &Bs[buf][ wid       * 512]);                 \
        GLL16(bg1 + (k0), &Bs[buf][(wid +  4) * 512]);                 \
        GLL16(bg2 + (k0), &Bs[buf][(wid +  8) * 512]);                 \
        GLL16(bg3 + (k0), &Bs[buf][(wid + 12) * 512]);                 \
    }

    // --- compute assignment: wave -> 32 rows x 64 cols ---
    const int wrow = (wid >> 1) * 32;
    const int wcol = (wid & 1) * 64;
    const int fr   = lane & 15;
    const int fg   = lane >> 4;

    f32x4 acc[2][4] = {};

    G1_ISSUE(0, 0);

    const int NT = DD / 64;   // 32
    for (int t = 0; t < NT; ++t) {
        __syncthreads();                       // drains vmcnt: buf[t&1] ready
        if (t + 1 < NT) G1_ISSUE((t + 1) & 1, (t + 1) * 64);
        const int cb = t & 1;
        #pragma unroll
        for (int kk = 0; kk < 2; ++kk) {
            half8 af[2], bf[4];
            #pragma unroll
            for (int i = 0; i < 2; ++i)
                af[i] = *(const half8*)&As[cb][(wrow + i*16 + fr) * 64 + kk*32 + fg*8];
            #pragma unroll
            for (int j = 0; j < 4; ++j)
                bf[j] = *(const half8*)&Bs[cb][(wcol + j*16 + fr) * 64 + kk*32 + fg*8];
            #pragma unroll
            for (int i = 0; i < 2; ++i)
                #pragma unroll
                for (int j = 0; j < 4; ++j)
                    acc[i][j] = __builtin_amdgcn_mfma_f32_16x16x32_f16(af[i], bf[j], acc[i][j], 0, 0, 0);
        }
    }

    // epilogue: bias + tanh -> f16 H
    #pragma unroll
    for (int i = 0; i < 2; ++i) {
        #pragma unroll
        for (int j = 0; j < 4; ++j) {
            int col = bn * 128 + wcol + j * 16 + fr;
            float bias = b1[col];
            #pragma unroll
            for (int r = 0; r < 4; ++r) {
                int row = bm * 64 + wrow + i * 16 + fg * 4 + r;
                Hout[(size_t)row * H1 + col] = (_Float16)tanhf(acc[i][j][r] + bias);
            }
        }
    }
    #undef G1_ISSUE
}

// ---------------------------------------------------------------------------
// GEMM2: out = H @ W2 + b2.  H f16 [12288][512], W2T f16 [768][512],
// out f32 [12288][768]. Tile 128x128, BK=64, wave = 64x64 (4x4 frags).
// Grid 576 = 2 blocks/CU (LDS 64KB).
// ---------------------------------------------------------------------------
__global__ __launch_bounds__(256) void gemm2_kernel(
    const _Float16* __restrict__ Hin,
    const _Float16* __restrict__ W2T,
    const float*    __restrict__ b2,
    float*          __restrict__ out)
{
    const int tid  = threadIdx.x;
    const int wid  = tid >> 6;
    const int lane = tid & 63;

    // 576 blocks, 72 per XCD
    const int logical = ((blockIdx.x & 7) * 72) + (blockIdx.x >> 3);
    const int bm = logical / 6;      // 0..95
    const int bn = logical % 6;      // 0..5

    __shared__ _Float16 As[2][128 * 64];   // 16KB per buf
    __shared__ _Float16 Bs[2][128 * 64];

    const int lrow = lane >> 3;
    const int lcol = (lane & 7) * 8;
    const _Float16* ag[4];
    const _Float16* bg[4];
    #pragma unroll
    for (int q = 0; q < 4; ++q) {
        ag[q] = Hin + (size_t)(bm * 128 + (wid + q * 4) * 8 + lrow) * H1 + lcol;
        bg[q] = W2T + (size_t)(bn * 128 + (wid + q * 4) * 8 + lrow) * H1 + lcol;
    }

    #define G2_ISSUE(buf, k0) {                                        \
        _Pragma("unroll")                                              \
        for (int q = 0; q < 4; ++q) {                                  \
            GLL16(ag[q] + (k0), &As[buf][(wid + q * 4) * 512]);        \
            GLL16(bg[q] + (k0), &Bs[buf][(wid + q * 4) * 512]);        \
        }                                                              \
    }

    const int wrow = (wid >> 1) * 64;
    const int wcol = (wid & 1) * 64;
    const int fr   = lane & 15;
    const int fg   = lane >> 4;

    f32x4 acc[4][4] = {};

    G2_ISSUE(0, 0);

    const int NT = H1 / 64;   // 8
    for (int t = 0; t < NT; ++t) {
        __syncthreads();
        if (t + 1 < NT) G2_ISSUE((t + 1) & 1, (t + 1) * 64);
        const int cb = t & 1;
        #pragma unroll
        for (int kk = 0; kk < 2; ++kk) {
            half8 af[4], bf[4];
            #pragma unroll
            for (int i = 0; i < 4; ++i)
                af[i] = *(const half8*)&As[cb][(wrow + i*16 + fr) * 64 + kk*32 + fg*8];
            #pragma unroll
            for (int j = 0; j < 4; ++j)
                bf[j] = *(const half8*)&Bs[cb][(wcol + j*16 + fr) * 64 + kk*32 + fg*8];
            #pragma unroll
            for (int i = 0; i < 4; ++i)
                #pragma unroll
                for (int j = 0; j < 4; ++j)
                    acc[i][j] = __builtin_amdgcn_mfma_f32_16x16x32_f16(af[i], bf[j], acc[i][j], 0, 0, 0);
        }
    }

    #pragma unroll
    for (int i = 0; i < 4; ++i) {
        #pragma unroll
        for (int j = 0; j < 4; ++j) {
            int col = bn * 128 + wcol + j * 16 + fr;
            float bias = b2[col];
            #pragma unroll
            for (int r = 0; r < 4; ++r) {
                int row = bm * 128 + wrow + i * 16 + fg * 4 + r;
                out[(size_t)row * H2 + col] = acc[i][j][r] + bias;
            }
        }
    }
    #undef G2_ISSUE
}

// ---------------------------------------------------------------------------
// Aux outputs: labels / type_ids / att_mask concatenations, written as floats
// ---------------------------------------------------------------------------
__global__ __launch_bounds__(256) void aux_kernel(
    const int* __restrict__ topic_ids,
    const int* __restrict__ input_ids,
    const int* __restrict__ tpw_type_ids,
    const int* __restrict__ type_ids,
    const int* __restrict__ tpw_att_mask,
    const int* __restrict__ attention_mask,
    float* __restrict__ out)
{
    int idx = blockIdx.x * 256 + threadIdx.x;
    if (idx >= MM) return;
    int b = idx / TT, t = idx % TT;
    int lab, ty, mk;
    if (t < PP) {
        lab = topic_ids[b * PP + t];
        ty  = tpw_type_ids[b * PP + t];
        mk  = tpw_att_mask[b * PP + t];
    } else {
        int u = t - PP;
        lab = input_ids[b * LL + u];
        ty  = type_ids[b * LL + u];
        mk  = attention_mask[b * LL + u];
    }
    out[OUT0 + idx]          = (float)lab;
    out[OUT0 + MM + idx]     = (float)ty;
    out[OUT0 + 2 * MM + idx] = (float)mk;
}

extern "C" void kernel_launch(void* const* d_in, const int* in_sizes, int n_in,
                              void* d_out, int out_size, void* d_ws, size_t ws_size,
                              hipStream_t stream) {
    const float* concat_output  = (const float*)d_in[0];
    const int*   input_ids      = (const int*)d_in[1];
    const int*   topic_ids      = (const int*)d_in[2];
    const int*   tpw_att_mask   = (const int*)d_in[3];
    const int*   tpw_type_ids   = (const int*)d_in[4];
    const int*   attention_mask = (const int*)d_in[5];
    const int*   type_ids       = (const int*)d_in[6];
    const float* token_table    = (const float*)d_in[7];
    const float* W1             = (const float*)d_in[8];
    const float* b1             = (const float*)d_in[9];
    const float* W2             = (const float*)d_in[10];
    const float* b2             = (const float*)d_in[11];
    float* out = (float*)d_out;

    _Float16* w1t = (_Float16*)d_ws;            // [512][2048]   2.0 MB
    _Float16* w2t = w1t + (size_t)H1 * DD;      // [768][512]    0.75 MB
    _Float16* Hws = w2t + (size_t)H2 * H1;      // [12288][512]  12.6 MB
    _Float16* A16 = Hws + (size_t)MM * H1;      // [12288][2048] 50.3 MB

    transpose_f16_kernel<<<dim3(H1 / 32, DD / 32), 256, 0, stream>>>(W1, w1t, DD, H1);
    transpose_f16_kernel<<<dim3(H2 / 32, H1 / 32), 256, 0, stream>>>(W2, w2t, H1, H2);
    aux_kernel<<<(MM + 255) / 256, 256, 0, stream>>>(
        topic_ids, input_ids, tpw_type_ids, type_ids, tpw_att_mask, attention_mask, out);
    gather_kernel<<<MM, 256, 0, stream>>>(
        token_table, topic_ids, input_ids, concat_output, A16);

    gemm1_kernel<<<(MM / 64) * (H1 / 128), 256, 0, stream>>>(A16, w1t, b1, Hws);
    gemm2_kernel<<<(MM / 128) * (H2 / 128), 256, 0, stream>>>(Hws, w2t, b2, out);
}

// Round 5
// 104.253 us; speedup vs baseline: 4.7969x; 1.1013x over previous
//
#include <hip/hip_runtime.h>
#include <math.h>

typedef _Float16 half8 __attribute__((ext_vector_type(8)));
typedef float f32x4 __attribute__((ext_vector_type(4)));

// Problem constants
#define BB 32
#define SS 8
#define PP 32
#define SENT 44
#define LL 352          // SS*SENT
#define TT 384          // PP+LL
#define DD 2048
#define H1 512
#define H2 768
#define MM (BB*TT)      // 12288
#define OUT0 (MM*H2)    // 9437184

// async global->LDS, 16B per lane, dest = wave-uniform base + lane*16
#define GLL16(g, l) __builtin_amdgcn_global_load_lds( \
    (const __attribute__((address_space(1))) void*)(g), \
    (__attribute__((address_space(3))) void*)(l), 16, 0, 0)

// ---------------------------------------------------------------------------
// Transpose + fp32->fp16 convert:  dst[C][R] = (f16) src[R][C]
// ---------------------------------------------------------------------------
__global__ __launch_bounds__(256) void transpose_f16_kernel(
    const float* __restrict__ src, _Float16* __restrict__ dst, int R, int C)
{
    __shared__ float tile[32][33];
    int c0 = blockIdx.x * 32;
    int r0 = blockIdx.y * 32;
    int tx = threadIdx.x & 31;
    int ty = threadIdx.x >> 5;   // 0..7
    #pragma unroll
    for (int i = 0; i < 4; ++i)
        tile[ty + i*8][tx] = src[(size_t)(r0 + ty + i*8) * C + c0 + tx];
    __syncthreads();
    #pragma unroll
    for (int i = 0; i < 4; ++i)
        dst[(size_t)(c0 + ty + i*8) * R + r0 + tx] = (_Float16)tile[tx][ty + i*8];
}

// ---------------------------------------------------------------------------
// GEMM1 (gather fused): H = tanh( gather(A) @ W1 + b1 )
// A virtual [12288,2048] fp32 (token_table gather + concat add), W1T f16
// [512][2048], H f16 [12288][512].
// Tile 64x256, BK=64, 256 thr = 4 waves, wave = 32x128 (2x8 frags).
// A reg-staged (convert fp32->f16, swizzled ds_write), 2-deep prefetch.
// B via global_load_lds with both-sides XOR swizzle (pre-swizzled source).
// LDS 80KB -> 2 blocks/CU; grid 384 (XCD-chunked, 48/XCD).
// ---------------------------------------------------------------------------
__global__ __launch_bounds__(256) void gemm1_kernel(
    const float*    __restrict__ token_table,
    const int*      __restrict__ topic_ids,
    const int*      __restrict__ input_ids,
    const float*    __restrict__ concat_output,
    const _Float16* __restrict__ W1T,
    const float*    __restrict__ b1,
    _Float16*       __restrict__ Hout)
{
    const int tid  = threadIdx.x;
    const int wid  = tid >> 6;
    const int lane = tid & 63;

    // XCD-chunked bijective swizzle: 384 blocks, 48 per XCD; both bn of a bm
    // are logical-adjacent -> same XCD.
    const int logical = ((blockIdx.x & 7) * 48) + (blockIdx.x >> 3);
    const int bm = logical >> 1;     // 0..191
    const int bn = logical & 1;      // 0..1

    __shared__ _Float16 As[2][64 * 64];     //  8KB per buf
    __shared__ _Float16 Bs[2][256 * 64];    // 32KB per buf

    // --- A gather setup: thread -> (row, k-quarter) ---
    const int arow = tid >> 2;          // 0..63
    const int akq  = (tid & 3) * 16;    // 0,16,32,48 (halfs == fp32 elems)
    const int aswz = (arow & 7) << 3;   // XOR swizzle, half units

    {
    }
    const int m = bm * 64 + arow;
    const int b = m / TT;
    const int t = m % TT;
    const float* aptr;
    const float* addp = nullptr;
    if (t < PP) {
        aptr = token_table + (size_t)topic_ids[b * PP + t] * DD;
    } else {
        int u = t - PP;
        aptr = token_table + (size_t)input_ids[b * LL + u] * DD;
        addp = concat_output + ((size_t)b * SS + (u / SENT)) * DD;
    }

    // --- B staging: per wave 8 GLL16 issues of 8 rows each ---
    const int rl = lane >> 3;           // 0..7 row within 8-row group
    const int cg = lane & 7;            // 16B granule within row
    // pre-swizzled global source: LDS granule (rl,cg) holds global granule cg^rl
    const _Float16* bsrc = W1T + (size_t)(bn * 256 + wid * 64 + rl) * DD
                               + ((cg ^ rl) << 3);

    #define G1B(buf, k0) {                                                 \
        _Pragma("unroll")                                                  \
        for (int q = 0; q < 8; ++q)                                        \
            GLL16(bsrc + (size_t)q * 8 * DD + (k0),                        \
                  &Bs[buf][(wid * 8 + q) * 512]);                          \
    }

    #define LOADA(S, k0) {                                                 \
        const float* ap = aptr + (k0) + akq;                               \
        float4 v0 = *(const float4*)(ap);                                  \
        float4 v1 = *(const float4*)(ap + 4);                              \
        float4 v2 = *(const float4*)(ap + 8);                              \
        float4 v3 = *(const float4*)(ap + 12);                             \
        if (addp) {                                                        \
            const float* cp = addp + (k0) + akq;                           \
            float4 c0 = *(const float4*)(cp);                              \
            float4 c1 = *(const float4*)(cp + 4);                          \
            float4 c2 = *(const float4*)(cp + 8);                          \
            float4 c3 = *(const float4*)(cp + 12);                         \
            v0.x += c0.x; v0.y += c0.y; v0.z += c0.z; v0.w += c0.w;        \
            v1.x += c1.x; v1.y += c1.y; v1.z += c1.z; v1.w += c1.w;        \
            v2.x += c2.x; v2.y += c2.y; v2.z += c2.z; v2.w += c2.w;        \
            v3.x += c3.x; v3.y += c3.y; v3.z += c3.z; v3.w += c3.w;        \
        }                                                                  \
        S[0]=v0.x; S[1]=v0.y; S[2]=v0.z; S[3]=v0.w;                        \
        S[4]=v1.x; S[5]=v1.y; S[6]=v1.z; S[7]=v1.w;                        \
        S[8]=v2.x; S[9]=v2.y; S[10]=v2.z; S[11]=v2.w;                      \
        S[12]=v3.x; S[13]=v3.y; S[14]=v3.z; S[15]=v3.w;                    \
    }

    #define WRITEA(S, buf) {                                               \
        half8 h0, h1;                                                      \
        _Pragma("unroll")                                                  \
        for (int j = 0; j < 8; ++j) { h0[j] = (_Float16)S[j];              \
                                      h1[j] = (_Float16)S[8 + j]; }        \
        *(half8*)&As[buf][(arow * 64 + akq) ^ aswz]     = h0;              \
        *(half8*)&As[buf][(arow * 64 + akq + 8) ^ aswz] = h1;              \
    }

    // --- compute assignment: wave -> 32 rows x 128 cols ---
    const int wrow = (wid >> 1) * 32;
    const int wcol = (wid & 1) * 128;
    const int fr   = lane & 15;
    const int fg   = lane >> 4;

    f32x4 acc[2][8] = {};

    #define MFMAP(buf) {                                                   \
        _Pragma("unroll")                                                  \
        for (int kk = 0; kk < 2; ++kk) {                                   \
            half8 af[2], bf[8];                                            \
            _Pragma("unroll")                                              \
            for (int i = 0; i < 2; ++i) {                                  \
                int row = wrow + i * 16 + fr;                              \
                af[i] = *(const half8*)&As[buf][                           \
                    (row * 64 + kk * 32 + fg * 8) ^ ((row & 7) << 3)];     \
            }                                                              \
            _Pragma("unroll")                                              \
            for (int j = 0; j < 8; ++j) {                                  \
                int row = wcol + j * 16 + fr;                              \
                bf[j] = *(const half8*)&Bs[buf][                           \
                    (row * 64 + kk * 32 + fg * 8) ^ ((row & 7) << 3)];     \
            }                                                              \
            _Pragma("unroll")                                              \
            for (int i = 0; i < 2; ++i)                                    \
                _Pragma("unroll")                                          \
                for (int j = 0; j < 8; ++j)                                \
                    acc[i][j] = __builtin_amdgcn_mfma_f32_16x16x32_f16(    \
                        af[i], bf[j], acc[i][j], 0, 0, 0);                 \
        }                                                                  \
    }

    float a0[16], a1[16];

    // prologue: B(0)->buf0, A(0)->a0, A(1)->a1, write A(0)
    G1B(0, 0);
    LOADA(a0, 0);
    LOADA(a1, 64);
    WRITEA(a0, 0);
    __syncthreads();

    // main loop: 32 K-steps as 16 double-phases
    for (int tt = 0; tt < 16; ++tt) {
        const int t2 = tt * 2;
        // even phase: compute buf0 (k-step t2)
        G1B(1, (t2 + 1) * 64);
        if (t2 + 2 < 32) LOADA(a0, (t2 + 2) * 64);
        MFMAP(0);
        WRITEA(a1, 1);
        __syncthreads();
        // odd phase: compute buf1 (k-step t2+1)
        if (t2 + 2 < 32) G1B(0, (t2 + 2) * 64);
        if (t2 + 3 < 32) LOADA(a1, (t2 + 3) * 64);
        MFMAP(1);
        if (t2 + 2 < 32) WRITEA(a0, 0);
        __syncthreads();
    }

    // epilogue: bias + tanh -> f16 H
    #pragma unroll
    for (int i = 0; i < 2; ++i) {
        #pragma unroll
        for (int j = 0; j < 8; ++j) {
            int col = bn * 256 + wcol + j * 16 + fr;
            float bias = b1[col];
            #pragma unroll
            for (int r = 0; r < 4; ++r) {
                int row = bm * 64 + wrow + i * 16 + fg * 4 + r;
                Hout[(size_t)row * H1 + col] = (_Float16)tanhf(acc[i][j][r] + bias);
            }
        }
    }
    #undef G1B
    #undef LOADA
    #undef WRITEA
    #undef MFMAP
}

// ---------------------------------------------------------------------------
// GEMM2: out = H @ W2 + b2.  H f16 [12288][512], W2T f16 [768][512],
// out f32 [12288][768]. Tile 128x128, BK=64, wave = 64x64 (4x4 frags).
// Both operands GLL16 with both-sides XOR swizzle. Grid 576, 2 blocks/CU.
// ---------------------------------------------------------------------------
__global__ __launch_bounds__(256) void gemm2_kernel(
    const _Float16* __restrict__ Hin,
    const _Float16* __restrict__ W2T,
    const float*    __restrict__ b2,
    float*          __restrict__ out)
{
    const int tid  = threadIdx.x;
    const int wid  = tid >> 6;
    const int lane = tid & 63;

    // 576 blocks, 72 per XCD
    const int logical = ((blockIdx.x & 7) * 72) + (blockIdx.x >> 3);
    const int bm = logical / 6;      // 0..95
    const int bn = logical % 6;      // 0..5

    __shared__ _Float16 As[2][128 * 64];   // 16KB per buf
    __shared__ _Float16 Bs[2][128 * 64];

    const int rl = lane >> 3;
    const int cg = lane & 7;
    // pre-swizzled sources
    const _Float16* asrc = Hin + (size_t)(bm * 128 + wid * 32 + rl) * H1
                               + ((cg ^ rl) << 3);
    const _Float16* bsrc = W2T + (size_t)(bn * 128 + wid * 32 + rl) * H1
                               + ((cg ^ rl) << 3);

    #define G2_ISSUE(buf, k0) {                                            \
        _Pragma("unroll")                                                  \
        for (int q = 0; q < 4; ++q) {                                      \
            GLL16(asrc + (size_t)q * 8 * H1 + (k0),                        \
                  &As[buf][(wid * 4 + q) * 512]);                          \
            GLL16(bsrc + (size_t)q * 8 * H1 + (k0),                        \
                  &Bs[buf][(wid * 4 + q) * 512]);                          \
        }                                                                  \
    }

    const int wrow = (wid >> 1) * 64;
    const int wcol = (wid & 1) * 64;
    const int fr   = lane & 15;
    const int fg   = lane >> 4;

    f32x4 acc[4][4] = {};

    G2_ISSUE(0, 0);

    const int NT = H1 / 64;   // 8
    for (int t = 0; t < NT; ++t) {
        __syncthreads();
        if (t + 1 < NT) G2_ISSUE((t + 1) & 1, (t + 1) * 64);
        const int cb = t & 1;
        #pragma unroll
        for (int kk = 0; kk < 2; ++kk) {
            half8 af[4], bf[4];
            #pragma unroll
            for (int i = 0; i < 4; ++i) {
                int row = wrow + i * 16 + fr;
                af[i] = *(const half8*)&As[cb][
                    (row * 64 + kk * 32 + fg * 8) ^ ((row & 7) << 3)];
            }
            #pragma unroll
            for (int j = 0; j < 4; ++j) {
                int row = wcol + j * 16 + fr;
                bf[j] = *(const half8*)&Bs[cb][
                    (row * 64 + kk * 32 + fg * 8) ^ ((row & 7) << 3)];
            }
            #pragma unroll
            for (int i = 0; i < 4; ++i)
                #pragma unroll
                for (int j = 0; j < 4; ++j)
                    acc[i][j] = __builtin_amdgcn_mfma_f32_16x16x32_f16(af[i], bf[j], acc[i][j], 0, 0, 0);
        }
    }

    #pragma unroll
    for (int i = 0; i < 4; ++i) {
        #pragma unroll
        for (int j = 0; j < 4; ++j) {
            int col = bn * 128 + wcol + j * 16 + fr;
            float bias = b2[col];
            #pragma unroll
            for (int r = 0; r < 4; ++r) {
                int row = bm * 128 + wrow + i * 16 + fg * 4 + r;
                out[(size_t)row * H2 + col] = acc[i][j][r] + bias;
            }
        }
    }
    #undef G2_ISSUE
}

// ---------------------------------------------------------------------------
// Aux outputs: labels / type_ids / att_mask concatenations, written as floats
// ---------------------------------------------------------------------------
__global__ __launch_bounds__(256) void aux_kernel(
    const int* __restrict__ topic_ids,
    const int* __restrict__ input_ids,
    const int* __restrict__ tpw_type_ids,
    const int* __restrict__ type_ids,
    const int* __restrict__ tpw_att_mask,
    const int* __restrict__ attention_mask,
    float* __restrict__ out)
{
    int idx = blockIdx.x * 256 + threadIdx.x;
    if (idx >= MM) return;
    int b = idx / TT, t = idx % TT;
    int lab, ty, mk;
    if (t < PP) {
        lab = topic_ids[b * PP + t];
        ty  = tpw_type_ids[b * PP + t];
        mk  = tpw_att_mask[b * PP + t];
    } else {
        int u = t - PP;
        lab = input_ids[b * LL + u];
        ty  = type_ids[b * LL + u];
        mk  = attention_mask[b * LL + u];
    }
    out[OUT0 + idx]          = (float)lab;
    out[OUT0 + MM + idx]     = (float)ty;
    out[OUT0 + 2 * MM + idx] = (float)mk;
}

extern "C" void kernel_launch(void* const* d_in, const int* in_sizes, int n_in,
                              void* d_out, int out_size, void* d_ws, size_t ws_size,
                              hipStream_t stream) {
    const float* concat_output  = (const float*)d_in[0];
    const int*   input_ids      = (const int*)d_in[1];
    const int*   topic_ids      = (const int*)d_in[2];
    const int*   tpw_att_mask   = (const int*)d_in[3];
    const int*   tpw_type_ids   = (const int*)d_in[4];
    const int*   attention_mask = (const int*)d_in[5];
    const int*   type_ids       = (const int*)d_in[6];
    const float* token_table    = (const float*)d_in[7];
    const float* W1             = (const float*)d_in[8];
    const float* b1             = (const float*)d_in[9];
    const float* W2             = (const float*)d_in[10];
    const float* b2             = (const float*)d_in[11];
    float* out = (float*)d_out;

    _Float16* w1t = (_Float16*)d_ws;            // [512][2048]   2.0 MB
    _Float16* w2t = w1t + (size_t)H1 * DD;      // [768][512]    0.75 MB
    _Float16* Hws = w2t + (size_t)H2 * H1;      // [12288][512]  12.6 MB

    transpose_f16_kernel<<<dim3(H1 / 32, DD / 32), 256, 0, stream>>>(W1, w1t, DD, H1);
    transpose_f16_kernel<<<dim3(H2 / 32, H1 / 32), 256, 0, stream>>>(W2, w2t, H1, H2);
    aux_kernel<<<(MM + 255) / 256, 256, 0, stream>>>(
        topic_ids, input_ids, tpw_type_ids, type_ids, tpw_att_mask, attention_mask, out);

    gemm1_kernel<<<(MM / 64) * (H1 / 256), 256, 0, stream>>>(
        token_table, topic_ids, input_ids, concat_output, w1t, b1, Hws);
    gemm2_kernel<<<(MM / 128) * (H2 / 128), 256, 0, stream>>>(Hws, w2t, b2, out);
}